// Round 4
// baseline (86.902 us; speedup 1.0000x reference)
//
#include <hip/hip_runtime.h>
#include <math.h>

#define NPTS 8192
#define GD 8
#define NCELL 512                  // GD^3
#define CELL_H (0.3f/(float)GD)    // 0.0375 > 0.02 alignment radius
#define INV_H ((float)GD/0.3f)
#define ALIGN_T 4.0e-4f            // 0.02^2
#define K5 5
#define K9 9
#define CAP 768                    // LDS box capacity (measured box ~430, +6-sigma ~557)
#define OWNCAP 96                  // own-cell capacity (avg 16, +6-sigma ~41)

// ws layout: float4[NCELL] partials (plain stores, no init) + 4-byte counter (memset)
#define WS_PART 0                  // float4[NCELL]: (flat, asum, acnt, dens)
#define WS_CNTR 8192               // uint: completion counter (only init'd bytes)

__device__ __forceinline__ void insert5(float (&d)[K5], float v) {
#pragma unroll
    for (int k = 0; k < K5; k++) { float lo = fminf(d[k], v); v = fmaxf(d[k], v); d[k] = lo; }
}
__device__ __forceinline__ void insert9(float (&d)[K9], float v) {
#pragma unroll
    for (int k = 0; k < K9; k++) { float lo = fminf(d[k], v); v = fmaxf(d[k], v); d[k] = lo; }
}

// dual interleaved extract-min over two K5 lists (R10-proven exact)
__device__ __forceinline__ void dual_merge5(const float (&dA)[K5], const float (&dB)[K5],
                                            float& s8A, float& d9A, float& s8B, float& d9B) {
    float a0=dA[0],a1=dA[1],a2=dA[2],a3=dA[3],a4=dA[4];
    float b0=dB[0],b1=dB[1],b2=dB[2],b3=dB[3],b4=dB[4];
    float sA=0.f, sB=0.f, mA=0.f, mB=0.f;
#pragma unroll
    for (int k = 0; k < 9; k++) {
        mA = a0; mB = b0;
#pragma unroll
        for (int o = 32; o > 0; o >>= 1) {
            mA = fminf(mA, __shfl_xor(mA, o, 64));
            mB = fminf(mB, __shfl_xor(mB, o, 64));
        }
        bool tA = (a0 == mA), tB = (b0 == mB);
        a0=tA?a1:a0; a1=tA?a2:a1; a2=tA?a3:a2; a3=tA?a4:a3; a4=tA?1e30f:a4;
        b0=tB?b1:b0; b1=tB?b2:b1; b2=tB?b3:b2; b3=tB?b4:b3; b4=tB?1e30f:b4;
        if (k >= 1) {
            sA += sqrtf(fmaxf(mA, 0.f) + 1e-12f);
            sB += sqrtf(fmaxf(mB, 0.f) + 1e-12f);
        }
    }
    s8A = sA; d9A = mA; s8B = sB; d9B = mB;
}

// serial extract-min over K9 (cold fallback only)
__device__ __forceinline__ void wave_merge9x(const float (&dd)[K9], float& s8, float& d9) {
    float t0=dd[0],t1=dd[1],t2=dd[2],t3=dd[3],t4=dd[4],t5=dd[5],t6=dd[6],t7=dd[7],t8=dd[8];
    float ssum = 0.f, m = 0.f;
#pragma unroll
    for (int k = 0; k < 9; k++) {
        m = t0;
#pragma unroll
        for (int o = 32; o > 0; o >>= 1) m = fminf(m, __shfl_xor(m, o, 64));
        bool take = (t0 == m);
        t0=take?t1:t0; t1=take?t2:t1; t2=take?t3:t2; t3=take?t4:t3;
        t4=take?t5:t4; t5=take?t6:t5; t6=take?t7:t6; t7=take?t8:t7;
        t8=take?1e30f:t8;
        if (k >= 1) ssum += sqrtf(fmaxf(m, 0.f) + 1e-12f);
    }
    s8 = ssum; d9 = m;
}

// ---------------- K1: one block per cell — gather + flatness + query + in-kernel finish ----------------
__global__ __launch_bounds__(512, 4) void gsr_main(
    const float* __restrict__ pos, const float* __restrict__ rot,
    const float* __restrict__ scl, const float* __restrict__ opa,
    unsigned char* __restrict__ ws, float* __restrict__ out)
{
    float4* partials = (float4*)(ws + WS_PART);
    unsigned int* counter = (unsigned int*)(ws + WS_CNTR);

    __shared__ float4 lp[CAP];
    __shared__ float4 lr[CAP];
    __shared__ int   ownSlot[OWNCAP];
    __shared__ float ownOpa[OWNCAP];
    __shared__ float red[8][3];
    __shared__ float sFlat;
    __shared__ unsigned int sPacked;   // member count (low16) | own count (high16)
    __shared__ int lastflag;

    const int tid = threadIdx.x;
    const int lane = tid & 63;
    const int wv = tid >> 6;
    const int c = blockIdx.x;
    const int cx = c >> 6, cy = (c >> 3) & 7, cz = c & 7;

    if (tid == 0) sPacked = 0u;
    __syncthreads();

    // ---- flatness slice: 16 points per block (wave 0, lanes 0..15) ----
    if (wv == 0) {
        float flat = 0.f;
        if (lane < 16) {
            int p = c*16 + lane;
            float ea = expf(scl[3*p]), eb = expf(scl[3*p+1]), ec = expf(scl[3*p+2]);
            float mn = fminf(ea, fminf(eb, ec));
            float mx = fmaxf(ea, fmaxf(eb, ec));
            float md = fminf(fmaxf(ea, eb), fmaxf(fminf(ea, eb), ec));
            flat = logf(mx/(mn+1e-8f)+1e-8f) + 0.1f/(fabsf(mx-md)+0.001f);
        }
#pragma unroll
        for (int o = 8; o > 0; o >>= 1) flat += __shfl_down(flat, o, 64);
        if (lane == 0) sFlat = flat;
    }

    // ---- gather: every block scans all points (L2-resident, 96 KB) ----
    // 4 points per thread per step via 3 float4 loads; single fused compaction scan.
    const float4* p4 = (const float4*)pos;
    for (int g = 0; g < 4; ++g) {
        const int q = g*512 + tid;               // points 4q .. 4q+3
        const float4 A = p4[3*q], B = p4[3*q+1], C = p4[3*q+2];
        float px[4] = {A.x, A.w, B.z, C.y};
        float py[4] = {A.y, B.x, B.w, C.z};
        float pz[4] = {A.z, B.y, C.x, C.w};
        bool mb[4], ob[4];
        int mloc[4], oloc[4];
        unsigned int mcnt = 0u, ocnt = 0u;
#pragma unroll
        for (int j = 0; j < 4; j++) {
            int ix = min((int)(px[j]*INV_H), GD-1);
            int iy = min((int)(py[j]*INV_H), GD-1);
            int iz = min((int)(pz[j]*INV_H), GD-1);
            mb[j] = (ix >= cx-1) & (ix <= cx+1) &
                    (iy >= cy-1) & (iy <= cy+1) &
                    (iz >= cz-1) & (iz <= cz+1);
            ob[j] = (ix == cx) & (iy == cy) & (iz == cz);
            mloc[j] = (int)mcnt;  mcnt += mb[j] ? 1u : 0u;
            oloc[j] = (int)ocnt;  ocnt += ob[j] ? 1u : 0u;
        }
        unsigned int packed = mcnt | (ocnt << 16);
        unsigned int incl = packed;
#pragma unroll
        for (int o = 1; o < 64; o <<= 1) {
            unsigned int v = __shfl_up(incl, o, 64);
            incl += (lane >= o) ? v : 0u;
        }
        const unsigned int excl = incl - packed;
        const unsigned int total = __shfl(incl, 63, 64);
        unsigned int oldv = 0u;
        if (lane == 0) oldv = atomicAdd(&sPacked, total);
        oldv = __shfl(oldv, 0, 64);
        const int mbase = (int)((oldv & 0xffffu) + (excl & 0xffffu));
        const int obase = (int)((oldv >> 16) + (excl >> 16));
#pragma unroll
        for (int j = 0; j < 4; j++) {
            if (mb[j]) {
                const int p = 4*q + j;
                const int slot = mbase + mloc[j];
                // identical fmaf shape as query dot product -> self d2 == 0 exactly
                float w = fmaf(px[j], px[j], fmaf(py[j], py[j], pz[j]*pz[j]));
                lp[slot] = make_float4(px[j], py[j], pz[j], w);
                lr[slot] = *(const float4*)(rot + 4*p);
                if (ob[j]) {
                    const int os = obase + oloc[j];
                    ownSlot[os] = slot;
                    ownOpa[os] = opa[p];
                }
            }
        }
    }
    __syncthreads();

    const int nbox  = (int)(sPacked & 0xffffu);
    const int nrows = (int)(sPacked >> 16);

    float asum = 0.f, acnt = 0.f, densAcc = 0.f;

    const int npairs = (nrows + 1) >> 1;
    for (int pi = wv; pi < npairs; pi += 8) {
        const int r0 = 2*pi;
        const int r1 = r0 + 1;
        const bool bval = (r1 < nrows);
        const int s0 = ownSlot[r0];
        const int s1 = bval ? ownSlot[r1] : s0;
        const float4 P0 = lp[s0];
        const float4 P1 = lp[s1];
        const float4 Q0 = lr[s0];
        const float4 Q1 = lr[s1];

        float dA[K5], dB[K5];
#pragma unroll
        for (int k = 0; k < K5; k++) { dA[k] = 1e30f; dB[k] = 1e30f; }

        for (int g = lane; g < nbox; g += 64) {
            float4 p = lp[g];
            float4 rt = lr[g];
            float dt0 = fmaf(P0.x, p.x, fmaf(P0.y, p.y, P0.z*p.z));
            float dt1 = fmaf(P1.x, p.x, fmaf(P1.y, p.y, P1.z*p.z));
            float cA = fmaf(-2.f, dt0, P0.w + p.w);   // d^2; self == 0.0f exactly
            float cB = fmaf(-2.f, dt1, P1.w + p.w);
            insert5(dA, cA);
            insert5(dB, cB);
            bool aA = (cA < ALIGN_T) & (cA != 0.0f);
            bool aB = (cB < ALIGN_T) & (cB != 0.0f) & bval;
            float dq0 = fmaf(Q0.x, rt.x, fmaf(Q0.y, rt.y, fmaf(Q0.z, rt.z, Q0.w*rt.w)));
            float dq1 = fmaf(Q1.x, rt.x, fmaf(Q1.y, rt.y, fmaf(Q1.z, rt.z, Q1.w*rt.w)));
            asum += aA ? (1.f - fabsf(dq0)) : 0.f;
            acnt += aA ? 1.f : 0.f;
            asum += aB ? (1.f - fabsf(dq1)) : 0.f;
            acnt += aB ? 1.f : 0.f;
        }

        float s8A, d9A, s8B, d9B;
        dual_merge5(dA, dB, s8A, d9A, s8B, d9B);

#pragma unroll
        for (int rr = 0; rr < 2; rr++) {
            if (rr == 1 && !bval) break;
            const float Px = rr ? P1.x : P0.x;
            const float Py = rr ? P1.y : P0.y;
            const float Pz = rr ? P1.z : P0.z;
            const float Pw = rr ? P1.w : P0.w;
            float s8 = rr ? s8B : s8A;
            float d9 = rr ? d9B : d9A;
            float cov = 1e30f;
            if (cx-1 > 0)    cov = fminf(cov, Px - (float)(cx-1)*CELL_H);
            if (cx+1 < GD-1) cov = fminf(cov, (float)(cx+2)*CELL_H - Px);
            if (cy-1 > 0)    cov = fminf(cov, Py - (float)(cy-1)*CELL_H);
            if (cy+1 < GD-1) cov = fminf(cov, (float)(cy+2)*CELL_H - Py);
            if (cz-1 > 0)    cov = fminf(cov, Pz - (float)(cz-1)*CELL_H);
            if (cz+1 < GD-1) cov = fminf(cov, (float)(cz+2)*CELL_H - Pz);
            if (!(d9 <= cov*cov)) {
                // cold exact fallback: ONE full scan over all points (L2-resident) — exact kNN
                float e[K9];
#pragma unroll
                for (int k = 0; k < K9; k++) e[k] = 1e30f;
                for (int o = lane; o < NPTS; o += 64) {
                    float x = pos[3*o], y = pos[3*o+1], z = pos[3*o+2];
                    float pw = fmaf(x, x, fmaf(y, y, z*z));
                    float dt = fmaf(Px, x, fmaf(Py, y, Pz*z));
                    float cc = fmaf(-2.f, dt, Pw + pw);
                    insert9(e, cc);
                }
                wave_merge9x(e, s8, d9);
            }
            if (lane == 0) {
                densAcc += fabsf(s8*0.125f - 0.01f) * ownOpa[r0 + rr];
            }
        }
    }

    // ---- block reduction of (asum, acnt, dens) across 8 waves ----
    float vals[3] = {asum, acnt, densAcc};
#pragma unroll
    for (int qi = 0; qi < 3; qi++) {
        float v = vals[qi];
        for (int o = 32; o > 0; o >>= 1) v += __shfl_down(v, o, 64);
        if (lane == 0) red[wv][qi] = v;
    }
    __syncthreads();
    if (tid == 0) {
        float t0=0,t1=0,t2=0;
        for (int w = 0; w < 8; w++) { t0+=red[w][0]; t1+=red[w][1]; t2+=red[w][2]; }
        partials[c] = make_float4(sFlat, t0, t1, t2);
        __threadfence();
        unsigned int old = atomicAdd(counter, 1u);
        lastflag = (old == NCELL-1) ? 1 : 0;
    }
    __syncthreads();

    // ---- last block finishes: identical lane-strided reduction as old gsr_final ----
    if (lastflag && wv == 0) {
        __threadfence();
        float f=0.f, a=0.f, n=0.f, d=0.f;
        for (int b = lane; b < NCELL; b += 64) {
            float4 pv = partials[b];
            f += pv.x; a += pv.y; n += pv.z; d += pv.w;
        }
#pragma unroll
        for (int o = 32; o > 0; o >>= 1) {
            f += __shfl_down(f, o, 64);
            a += __shfl_down(a, o, 64);
            n += __shfl_down(n, o, 64);
            d += __shfl_down(d, o, 64);
        }
        if (lane == 0) {
            float flat_loss = -f / (float)NPTS;
            float align_loss = (n > 0.f) ? (a/n) : 0.f;
            float dens_loss = d / (float)NPTS;
            out[0] = 1.0f*flat_loss + 0.5f*align_loss + 0.2f*dens_loss;
        }
    }
}

extern "C" void kernel_launch(void* const* d_in, const int* in_sizes, int n_in,
                              void* d_out, int out_size, void* d_ws, size_t ws_size,
                              hipStream_t stream) {
    const float* pos = (const float*)d_in[0];
    const float* rot = (const float*)d_in[1];
    const float* scl = (const float*)d_in[2];
    const float* opa = (const float*)d_in[3];
    unsigned char* ws = (unsigned char*)d_ws;

    hipMemsetAsync(ws + WS_CNTR, 0, 4, stream);   // only the completion counter
    gsr_main<<<NCELL, 512, 0, stream>>>(pos, rot, scl, opa, ws, (float*)d_out);
}

// Round 5
// 84.974 us; speedup vs baseline: 1.0227x; 1.0227x over previous
//
#include <hip/hip_runtime.h>
#include <math.h>

#define NPTS 8192
#define GD 8
#define NCELL 512                  // GD^3
#define CELL_H (0.3f/(float)GD)    // 0.0375 > 0.02 alignment radius
#define INV_H ((float)GD/0.3f)
#define ALIGN_T 4.0e-4f            // 0.02^2
#define K5 5
#define K9 9
#define CAP 768                    // LDS box capacity (measured box ~430, +6-sigma ~557)
#define OWNCAP 96                  // own-cell capacity (avg 16, +6-sigma ~41)

// ws layout: ONLY per-block partials — no init required (plain stores)
#define WS_PART 0                  // float4[NCELL]: (flat, asum, acnt, dens)

__device__ __forceinline__ void insert5(float (&d)[K5], float v) {
#pragma unroll
    for (int k = 0; k < K5; k++) { float lo = fminf(d[k], v); v = fmaxf(d[k], v); d[k] = lo; }
}
__device__ __forceinline__ void insert9(float (&d)[K9], float v) {
#pragma unroll
    for (int k = 0; k < K9; k++) { float lo = fminf(d[k], v); v = fmaxf(d[k], v); d[k] = lo; }
}

// dual interleaved extract-min over two K5 lists (R10-proven exact)
__device__ __forceinline__ void dual_merge5(const float (&dA)[K5], const float (&dB)[K5],
                                            float& s8A, float& d9A, float& s8B, float& d9B) {
    float a0=dA[0],a1=dA[1],a2=dA[2],a3=dA[3],a4=dA[4];
    float b0=dB[0],b1=dB[1],b2=dB[2],b3=dB[3],b4=dB[4];
    float sA=0.f, sB=0.f, mA=0.f, mB=0.f;
#pragma unroll
    for (int k = 0; k < 9; k++) {
        mA = a0; mB = b0;
#pragma unroll
        for (int o = 32; o > 0; o >>= 1) {
            mA = fminf(mA, __shfl_xor(mA, o, 64));
            mB = fminf(mB, __shfl_xor(mB, o, 64));
        }
        bool tA = (a0 == mA), tB = (b0 == mB);
        a0=tA?a1:a0; a1=tA?a2:a1; a2=tA?a3:a2; a3=tA?a4:a3; a4=tA?1e30f:a4;
        b0=tB?b1:b0; b1=tB?b2:b1; b2=tB?b3:b2; b3=tB?b4:b3; b4=tB?1e30f:b4;
        if (k >= 1) {
            sA += sqrtf(fmaxf(mA, 0.f) + 1e-12f);
            sB += sqrtf(fmaxf(mB, 0.f) + 1e-12f);
        }
    }
    s8A = sA; d9A = mA; s8B = sB; d9B = mB;
}

// serial extract-min over K9 (cold fallback only)
__device__ __forceinline__ void wave_merge9x(const float (&dd)[K9], float& s8, float& d9) {
    float t0=dd[0],t1=dd[1],t2=dd[2],t3=dd[3],t4=dd[4],t5=dd[5],t6=dd[6],t7=dd[7],t8=dd[8];
    float ssum = 0.f, m = 0.f;
#pragma unroll
    for (int k = 0; k < 9; k++) {
        m = t0;
#pragma unroll
        for (int o = 32; o > 0; o >>= 1) m = fminf(m, __shfl_xor(m, o, 64));
        bool take = (t0 == m);
        t0=take?t1:t0; t1=take?t2:t1; t2=take?t3:t2; t3=take?t4:t3;
        t4=take?t5:t4; t5=take?t6:t5; t6=take?t7:t6; t7=take?t8:t7;
        t8=take?1e30f:t8;
        if (k >= 1) ssum += sqrtf(fmaxf(m, 0.f) + 1e-12f);
    }
    s8 = ssum; d9 = m;
}

// ---------------- K1: one block per cell — gather box from L2 + flatness + query ----------------
__global__ __launch_bounds__(512, 4) void gsr_main(
    const float* __restrict__ pos, const float* __restrict__ rot,
    const float* __restrict__ scl, const float* __restrict__ opa,
    unsigned char* __restrict__ ws)
{
    float4* partials = (float4*)(ws + WS_PART);

    __shared__ float4 lp[CAP];
    __shared__ float4 lr[CAP];
    __shared__ int   ownSlot[OWNCAP];
    __shared__ float ownOpa[OWNCAP];
    __shared__ float red[8][3];
    __shared__ float sFlat;
    __shared__ unsigned int sPacked;   // member count (low16) | own count (high16)

    const int tid = threadIdx.x;
    const int lane = tid & 63;
    const int wv = tid >> 6;
    const int c = blockIdx.x;
    const int cx = c >> 6, cy = (c >> 3) & 7, cz = c & 7;

    // float-domain membership bounds — exact equivalent of min((int)t, 7)-based tests,
    // including the t==8.0 rounding edge (clamp makes upper bound vacuous for cx>=6 / cx==7)
    const float mlx = (float)(cx-1), mly = (float)(cy-1), mlz = (float)(cz-1);
    const float mux = (cx >= 6) ? 1e9f : (float)(cx+2);
    const float muy = (cy >= 6) ? 1e9f : (float)(cy+2);
    const float muz = (cz >= 6) ? 1e9f : (float)(cz+2);
    const float olx = (float)cx, oly = (float)cy, olz = (float)cz;
    const float oux = (cx == 7) ? 1e9f : (float)(cx+1);
    const float ouy = (cy == 7) ? 1e9f : (float)(cy+1);
    const float ouz = (cz == 7) ? 1e9f : (float)(cz+1);

    if (tid == 0) sPacked = 0u;
    __syncthreads();

    // ---- flatness slice: 16 points per block (wave 0, lanes 0..15) ----
    if (wv == 0) {
        float flat = 0.f;
        if (lane < 16) {
            int p = c*16 + lane;
            float ea = expf(scl[3*p]), eb = expf(scl[3*p+1]), ec = expf(scl[3*p+2]);
            float mn = fminf(ea, fminf(eb, ec));
            float mx = fmaxf(ea, fmaxf(eb, ec));
            float md = fminf(fmaxf(ea, eb), fmaxf(fminf(ea, eb), ec));
            flat = logf(mx/(mn+1e-8f)+1e-8f) + 0.1f/(fabsf(mx-md)+0.001f);
        }
#pragma unroll
        for (int o = 8; o > 0; o >>= 1) flat += __shfl_down(flat, o, 64);
        if (lane == 0) sFlat = flat;
    }

    // ---- gather: every block scans all points (L2-resident, 96 KB) ----
    // 4 points per thread per step via 3 float4 loads; single fused compaction scan.
    const float4* p4 = (const float4*)pos;
    for (int g = 0; g < 4; ++g) {
        const int q = g*512 + tid;               // points 4q .. 4q+3
        const float4 A = p4[3*q], B = p4[3*q+1], C = p4[3*q+2];
        float px[4] = {A.x, A.w, B.z, C.y};
        float py[4] = {A.y, B.x, B.w, C.z};
        float pz[4] = {A.z, B.y, C.x, C.w};
        bool mb[4], ob[4];
        int mloc[4], oloc[4];
        unsigned int mcnt = 0u, ocnt = 0u;
#pragma unroll
        for (int j = 0; j < 4; j++) {
            float tx = px[j]*INV_H, ty = py[j]*INV_H, tz = pz[j]*INV_H;
            mb[j] = (tx >= mlx) & (tx < mux) &
                    (ty >= mly) & (ty < muy) &
                    (tz >= mlz) & (tz < muz);
            ob[j] = (tx >= olx) & (tx < oux) &
                    (ty >= oly) & (ty < ouy) &
                    (tz >= olz) & (tz < ouz);
            mloc[j] = (int)mcnt;  mcnt += mb[j] ? 1u : 0u;
            oloc[j] = (int)ocnt;  ocnt += ob[j] ? 1u : 0u;
        }
        unsigned int packed = mcnt | (ocnt << 16);
        unsigned int incl = packed;
#pragma unroll
        for (int o = 1; o < 64; o <<= 1) {
            unsigned int v = __shfl_up(incl, o, 64);
            incl += (lane >= o) ? v : 0u;
        }
        const unsigned int excl = incl - packed;
        const unsigned int total = __shfl(incl, 63, 64);
        unsigned int oldv = 0u;
        if (lane == 0) oldv = atomicAdd(&sPacked, total);
        oldv = __shfl(oldv, 0, 64);
        const int mbase = (int)((oldv & 0xffffu) + (excl & 0xffffu));
        const int obase = (int)((oldv >> 16) + (excl >> 16));
#pragma unroll
        for (int j = 0; j < 4; j++) {
            if (mb[j]) {
                const int p = 4*q + j;
                const int slot = mbase + mloc[j];
                // identical fmaf shape as query dot product -> self d2 == 0 exactly
                float w = fmaf(px[j], px[j], fmaf(py[j], py[j], pz[j]*pz[j]));
                lp[slot] = make_float4(px[j], py[j], pz[j], w);
                lr[slot] = *(const float4*)(rot + 4*p);
                if (ob[j]) {
                    const int os = obase + oloc[j];
                    ownSlot[os] = slot;
                    ownOpa[os] = opa[p];
                }
            }
        }
    }
    __syncthreads();

    const int nbox  = (int)(sPacked & 0xffffu);
    const int nrows = (int)(sPacked >> 16);

    float asum = 0.f, acnt = 0.f, densAcc = 0.f;

    const int npairs = (nrows + 1) >> 1;
    for (int pi = wv; pi < npairs; pi += 8) {
        const int r0 = 2*pi;
        const int r1 = r0 + 1;
        const bool bval = (r1 < nrows);
        const int s0 = ownSlot[r0];
        const int s1 = bval ? ownSlot[r1] : s0;
        const float4 P0 = lp[s0];
        const float4 P1 = lp[s1];
        const float4 Q0 = lr[s0];
        const float4 Q1 = lr[s1];

        float dA[K5], dB[K5];
#pragma unroll
        for (int k = 0; k < K5; k++) { dA[k] = 1e30f; dB[k] = 1e30f; }

        for (int g = lane; g < nbox; g += 64) {
            float4 p = lp[g];
            float4 rt = lr[g];
            float dt0 = fmaf(P0.x, p.x, fmaf(P0.y, p.y, P0.z*p.z));
            float dt1 = fmaf(P1.x, p.x, fmaf(P1.y, p.y, P1.z*p.z));
            float cA = fmaf(-2.f, dt0, P0.w + p.w);   // d^2; self == 0.0f exactly
            float cB = fmaf(-2.f, dt1, P1.w + p.w);
            insert5(dA, cA);
            insert5(dB, cB);
            bool aA = (cA < ALIGN_T) & (cA != 0.0f);
            bool aB = (cB < ALIGN_T) & (cB != 0.0f) & bval;
            float dq0 = fmaf(Q0.x, rt.x, fmaf(Q0.y, rt.y, fmaf(Q0.z, rt.z, Q0.w*rt.w)));
            float dq1 = fmaf(Q1.x, rt.x, fmaf(Q1.y, rt.y, fmaf(Q1.z, rt.z, Q1.w*rt.w)));
            asum += aA ? (1.f - fabsf(dq0)) : 0.f;
            acnt += aA ? 1.f : 0.f;
            asum += aB ? (1.f - fabsf(dq1)) : 0.f;
            acnt += aB ? 1.f : 0.f;
        }

        float s8A, d9A, s8B, d9B;
        dual_merge5(dA, dB, s8A, d9A, s8B, d9B);

#pragma unroll
        for (int rr = 0; rr < 2; rr++) {
            if (rr == 1 && !bval) break;
            const float Px = rr ? P1.x : P0.x;
            const float Py = rr ? P1.y : P0.y;
            const float Pz = rr ? P1.z : P0.z;
            const float Pw = rr ? P1.w : P0.w;
            float s8 = rr ? s8B : s8A;
            float d9 = rr ? d9B : d9A;
            float cov = 1e30f;
            if (cx-1 > 0)    cov = fminf(cov, Px - (float)(cx-1)*CELL_H);
            if (cx+1 < GD-1) cov = fminf(cov, (float)(cx+2)*CELL_H - Px);
            if (cy-1 > 0)    cov = fminf(cov, Py - (float)(cy-1)*CELL_H);
            if (cy+1 < GD-1) cov = fminf(cov, (float)(cy+2)*CELL_H - Py);
            if (cz-1 > 0)    cov = fminf(cov, Pz - (float)(cz-1)*CELL_H);
            if (cz+1 < GD-1) cov = fminf(cov, (float)(cz+2)*CELL_H - Pz);
            if (!(d9 <= cov*cov)) {
                // cold exact fallback: ONE full scan over all points (L2-resident) — exact kNN
                float e[K9];
#pragma unroll
                for (int k = 0; k < K9; k++) e[k] = 1e30f;
                for (int o = lane; o < NPTS; o += 64) {
                    float x = pos[3*o], y = pos[3*o+1], z = pos[3*o+2];
                    float pw = fmaf(x, x, fmaf(y, y, z*z));
                    float dt = fmaf(Px, x, fmaf(Py, y, Pz*z));
                    float cc = fmaf(-2.f, dt, Pw + pw);
                    insert9(e, cc);
                }
                wave_merge9x(e, s8, d9);
            }
            if (lane == 0) {
                densAcc += fabsf(s8*0.125f - 0.01f) * ownOpa[r0 + rr];
            }
        }
    }

    // ---- block reduction of (asum, acnt, dens) across 8 waves; plain store of partial ----
    float vals[3] = {asum, acnt, densAcc};
#pragma unroll
    for (int qi = 0; qi < 3; qi++) {
        float v = vals[qi];
        for (int o = 32; o > 0; o >>= 1) v += __shfl_down(v, o, 64);
        if (lane == 0) red[wv][qi] = v;
    }
    __syncthreads();
    if (tid == 0) {
        float t0=0,t1=0,t2=0;
        for (int w = 0; w < 8; w++) { t0+=red[w][0]; t1+=red[w][1]; t2+=red[w][2]; }
        partials[c] = make_float4(sFlat, t0, t1, t2);
    }
}

// ---------------- K2: one wave reduces 512 partials ----------------
__global__ __launch_bounds__(64) void gsr_final(
    const unsigned char* __restrict__ ws, float* __restrict__ out)
{
    const float4* partials = (const float4*)(ws + WS_PART);
    const int lane = threadIdx.x;
    float f=0.f, a=0.f, n=0.f, d=0.f;
    for (int b = lane; b < NCELL; b += 64) {
        float4 pv = partials[b];
        f += pv.x; a += pv.y; n += pv.z; d += pv.w;
    }
#pragma unroll
    for (int o = 32; o > 0; o >>= 1) {
        f += __shfl_down(f, o, 64);
        a += __shfl_down(a, o, 64);
        n += __shfl_down(n, o, 64);
        d += __shfl_down(d, o, 64);
    }
    if (lane == 0) {
        float flat_loss = -f / (float)NPTS;
        float align_loss = (n > 0.f) ? (a/n) : 0.f;
        float dens_loss = d / (float)NPTS;
        out[0] = 1.0f*flat_loss + 0.5f*align_loss + 0.2f*dens_loss;
    }
}

extern "C" void kernel_launch(void* const* d_in, const int* in_sizes, int n_in,
                              void* d_out, int out_size, void* d_ws, size_t ws_size,
                              hipStream_t stream) {
    const float* pos = (const float*)d_in[0];
    const float* rot = (const float*)d_in[1];
    const float* scl = (const float*)d_in[2];
    const float* opa = (const float*)d_in[3];
    unsigned char* ws = (unsigned char*)d_ws;

    gsr_main <<<NCELL, 512, 0, stream>>>(pos, rot, scl, opa, ws);
    gsr_final<<<1, 64, 0, stream>>>(ws, (float*)d_out);
}